// Round 2
// baseline (309.283 us; speedup 1.0000x reference)
//
#include <hip/hip_runtime.h>
#include <hip/hip_bf16.h>
#include <stdint.h>

typedef unsigned short u16;
using bf16x8 = __attribute__((ext_vector_type(8))) short;
using f32x4  = __attribute__((ext_vector_type(4))) float;

#define DEVI static __device__ __forceinline__

constexpr int CB = 16;     // batch
constexpr int CC = 256;    // channels
constexpr int CN = 4096;   // tokens (64*64)
constexpr int CH = 4;      // heads

DEVI u16 f2b(float f){
  union { float f; uint32_t u; } v; v.f = f;
  return (u16)((v.u + 0x7FFFu + ((v.u >> 16) & 1u)) >> 16);
}

// ---------------- prep: weights -> bf16, BN constants ----------------
__global__ __launch_bounds__(256) void k_prep_w(const float* __restrict__ qkv, const float* __restrict__ pj,
    const float* __restrict__ c1, const float* __restrict__ c2,
    u16* __restrict__ qkvb, u16* __restrict__ pjb, u16* __restrict__ c1b, u16* __restrict__ c2b){
  int id = blockIdx.x * 256 + threadIdx.x;
  if (id < 65536) qkvb[id] = f2b(qkv[id]);
  else if (id < 131072) pjb[id - 65536] = f2b(pj[id - 65536]);
  else if (id < 262144) c1b[id - 131072] = f2b(c1[id - 131072]);
  else c2b[id - 262144] = f2b(c2[id - 262144]);
}

__global__ __launch_bounds__(256) void k_prep_bn(const float* __restrict__ g1,const float* __restrict__ b1,
    const float* __restrict__ m1,const float* __restrict__ v1,
    const float* __restrict__ g2,const float* __restrict__ b2,
    const float* __restrict__ m2,const float* __restrict__ v2,
    float* __restrict__ s1,float* __restrict__ o1,float* __restrict__ s2,float* __restrict__ o2){
  int id = blockIdx.x*256 + threadIdx.x;
  if (id < 512){ float s = g1[id] * rsqrtf(v1[id] + 1e-5f); s1[id] = s; o1[id] = b1[id] - m1[id]*s; }
  else if (id < 768){ int c = id - 512; float s = g2[c] * rsqrtf(v2[c] + 1e-5f); s2[c] = s; o2[c] = b2[c] - m2[c]*s; }
}

// ---------------- transpose x [b][c][n] -> bf16 [b][n][c] ----------------
__global__ __launch_bounds__(256) void k_tr(const float* __restrict__ x, u16* __restrict__ xb){
  __shared__ float t[32][33];
  int b = blockIdx.x, c0 = blockIdx.y*32, n0 = blockIdx.z*32;
  int tr = threadIdx.x >> 5, tc = threadIdx.x & 31;
  const float* xp = x + ((size_t)b*CC + c0)*CN + n0;
  #pragma unroll
  for (int p=0;p<4;p++) t[tr + p*8][tc] = xp[(size_t)(tr + p*8)*CN + tc];
  __syncthreads();
  u16* op = xb + ((size_t)b*CN + n0)*CC + c0;
  #pragma unroll
  for (int p=0;p<4;p++) op[(size_t)(tr + p*8)*CC + tc] = f2b(t[tc][tr + p*8]);
}

// ---------------- GEMM: C[m][n] = sum_k A[m][k] * Act[b][n][k] ----------------
// A: [M_][K_] bf16 row-major. Act: [CB][CN][K_] bf16. 128x128 tile, BK=64,
// 4 waves, mfma 16x16x32, global_load_lds w/ XOR-swizzled source (rule #21).
// EPI 0: write fp32 of[b][n][M_] (float4)
// EPI 1: r = v + e0[c] + e1[b][c][n]; of[b][c][n]=r (fp32); ob[b][n][M_]=bf16(r)
// EPI 2: r = silu(v*e0[c]+e1[c]); ob[b][n][M_] = bf16(r)
// EPI 3: of[b][c][n] = v*e0[c]+e1[c] + e2[b][c][n]   (of may alias e2)
template<int M_, int K_, int EPI>
__global__ __launch_bounds__(256) void k_gemm(
    const u16* __restrict__ Aw, const u16* __restrict__ Act,
    float* of, u16* __restrict__ ob,
    const float* __restrict__ e0, const float* __restrict__ e1,
    const float* e2)
{
  __shared__ __align__(16) u16 As[128*64];
  __shared__ __align__(16) u16 Bs[128*64];
  const int t = threadIdx.x;
  const int lane = t & 63, wave = t >> 6;
  const int wr = wave >> 1, wc = wave & 1;
  const int lg = lane >> 4, lr = lane & 15;
  const int n0 = blockIdx.x * 128, m0 = blockIdx.y * 128, b = blockIdx.z;
  const u16* Ag = Aw + (size_t)m0 * K_;
  const u16* Bg = Act + ((size_t)b * CN + n0) * K_;
  f32x4 acc[4][4] = {};
  for (int kt = 0; kt < K_/64; ++kt){
    #pragma unroll
    for (int i=0;i<4;i++){
      int off = (i*256 + t) * 8;
      int m = off >> 6, gq = (off >> 3) & 7;
      int kk = (gq ^ (m & 7)) * 8;            // inverse-swizzled global k
      __builtin_amdgcn_global_load_lds(
        (__attribute__((address_space(1))) void*)(Ag + (size_t)m*K_ + kt*64 + kk),
        (__attribute__((address_space(3))) void*)(As + (i*256 + wave*64)*8), 16, 0, 0);
      __builtin_amdgcn_global_load_lds(
        (__attribute__((address_space(1))) void*)(Bg + (size_t)m*K_ + kt*64 + kk),
        (__attribute__((address_space(3))) void*)(Bs + (i*256 + wave*64)*8), 16, 0, 0);
    }
    __syncthreads();
    #pragma unroll
    for (int s=0;s<2;s++){
      bf16x8 af[4], bfv[4];
      #pragma unroll
      for (int mi=0;mi<4;mi++){
        int r = wr*64 + mi*16 + lr;
        af[mi] = *(const bf16x8*)(As + r*64 + (((s*4+lg) ^ (r & 7)) * 8));
      }
      #pragma unroll
      for (int ni=0;ni<4;ni++){
        int r = wc*64 + ni*16 + lr;
        bfv[ni] = *(const bf16x8*)(Bs + r*64 + (((s*4+lg) ^ (r & 7)) * 8));
      }
      #pragma unroll
      for (int mi=0;mi<4;mi++)
        #pragma unroll
        for (int ni=0;ni<4;ni++)
          acc[mi][ni] = __builtin_amdgcn_mfma_f32_16x16x32_bf16(af[mi], bfv[ni], acc[mi][ni], 0, 0, 0);
    }
    __syncthreads();
  }
  #pragma unroll
  for (int mi=0;mi<4;mi++){
    #pragma unroll
    for (int ni=0;ni<4;ni++){
      const int mb = m0 + wr*64 + mi*16 + lg*4;
      const int n  = n0 + wc*64 + ni*16 + lr;
      f32x4 v = acc[mi][ni];
      if constexpr (EPI == 0){
        *(f32x4*)(of + ((size_t)b*CN + n)*M_ + mb) = v;
      } else if constexpr (EPI == 1){
        float r[4];
        #pragma unroll
        for (int j=0;j<4;j++){
          size_t ix = ((size_t)b*CC + mb + j)*CN + n;
          r[j] = v[j] + e0[mb + j] + e1[ix];
          of[ix] = r[j];
        }
        ushort4 u; u.x=f2b(r[0]); u.y=f2b(r[1]); u.z=f2b(r[2]); u.w=f2b(r[3]);
        *(ushort4*)(ob + ((size_t)b*CN + n)*M_ + mb) = u;
      } else if constexpr (EPI == 2){
        ushort4 u;
        #pragma unroll
        for (int j=0;j<4;j++){
          float r = v[j]*e0[mb+j] + e1[mb+j];
          r = r / (1.f + __expf(-r));
          ((u16*)&u)[j] = f2b(r);
        }
        *(ushort4*)(ob + ((size_t)b*CN + n)*M_ + mb) = u;
      } else {
        #pragma unroll
        for (int j=0;j<4;j++){
          size_t ix = ((size_t)b*CC + mb + j)*CN + n;
          float rr = v[j]*e0[mb+j] + e1[mb+j] + e2[ix];
          of[ix] = rr;
        }
      }
    }
  }
}

// ---------------- stats over W [b][n][c] fp32 ----------------
__global__ __launch_bounds__(256) void k_nrm2(const float* __restrict__ W, float* __restrict__ nrm2){
  int b = blockIdx.x, nb = blockIdx.y, c = threadIdx.x;
  const float* p = W + ((size_t)b*CN + (size_t)nb*128)*CC + c;
  float s = 0.f;
  #pragma unroll 4
  for (int i=0;i<128;i++){ float w = p[(size_t)i*CC]; s += w*w; }
  atomicAdd(&nrm2[b*CC + c], s);
}

__global__ __launch_bounds__(256) void k_pi(const float* __restrict__ W, const float* __restrict__ nrm2,
    const float* __restrict__ temp, float* __restrict__ Pi, float* __restrict__ sumPi){
  int b = blockIdx.x, n0 = blockIdx.y * 64;
  int lane = threadIdx.x & 63, wave = threadIdx.x >> 6;
  int grp = lane >> 4, gl = lane & 15;
  float th = temp[grp];
  const float* nr = nrm2 + b*CC + 4*lane;
  float i0 = 1.f / fmaxf(nr[0], 1e-24f);
  float i1 = 1.f / fmaxf(nr[1], 1e-24f);
  float i2 = 1.f / fmaxf(nr[2], 1e-24f);
  float i3 = 1.f / fmaxf(nr[3], 1e-24f);
  float accp = 0.f;
  for (int i=0;i<16;i++){
    int n = n0 + wave*16 + i;
    const float4 wv = *(const float4*)(W + ((size_t)b*CN + n)*CC + 4*lane);
    float s = wv.x*wv.x*i0 + wv.y*wv.y*i1 + wv.z*wv.z*i2 + wv.w*wv.w*i3;
    #pragma unroll
    for (int off=1; off<16; off<<=1) s += __shfl_xor(s, off);
    s *= th;
    float s0=__shfl(s,0), sg1=__shfl(s,16), sg2=__shfl(s,32), sg3=__shfl(s,48);
    float mx = fmaxf(fmaxf(s0,sg1), fmaxf(sg2,sg3));
    float e0=__expf(s0-mx), e1=__expf(sg1-mx), e2=__expf(sg2-mx), e3=__expf(sg3-mx);
    float den = e0+e1+e2+e3;
    float eh = (grp==0)?e0:(grp==1)?e1:(grp==2)?e2:e3;
    float pih = eh/den;
    if (gl == 0){ Pi[((size_t)b*CH + grp)*CN + n] = pih; accp += pih; }
  }
  if (gl == 0) atomicAdd(&sumPi[b*CH + grp], accp);
}

__global__ __launch_bounds__(256) void k_dots(const float* __restrict__ W, const float* __restrict__ Pi,
    float* __restrict__ dots){
  int b = blockIdx.x, nb = blockIdx.y, c = threadIdx.x;
  int h = c >> 6;
  const float* p = W + ((size_t)b*CN + (size_t)nb*128)*CC + c;
  const float* pp = Pi + ((size_t)b*CH + h)*CN + (size_t)nb*128;
  float s = 0.f;
  #pragma unroll 4
  for (int i=0;i<128;i++){ float w = p[(size_t)i*CC]; s += pp[i]*w*w; }
  atomicAdd(&dots[b*CC + c], s);
}

__global__ __launch_bounds__(256) void k_attn(const float* __restrict__ dots, const float* __restrict__ sumPi,
    float* __restrict__ attnv){
  int b = blockIdx.x, c = threadIdx.x, h = c >> 6;
  attnv[b*CC + c] = 1.f / (1.f + dots[b*CC + c] / (sumPi[b*CH + h] + 1e-8f));
}

__global__ __launch_bounds__(256) void k_outc(const float* __restrict__ W, const float* __restrict__ Pi,
    const float* __restrict__ attnv, u16* __restrict__ oc){
  size_t id = (size_t)blockIdx.x * 256 + threadIdx.x;
  int c = ((int)(id & 63)) * 4;
  int n = (int)((id >> 6) & (CN - 1));
  int b = (int)(id >> 18);
  int h = c >> 6;
  const float4 w = *(const float4*)(W + ((size_t)b*CN + n)*CC + c);
  float pi = Pi[((size_t)b*CH + h)*CN + n];
  const float4 at = *(const float4*)(attnv + b*CC + c);
  ushort4 u;
  u.x = f2b(-w.x * pi * at.x);
  u.y = f2b(-w.y * pi * at.y);
  u.z = f2b(-w.z * pi * at.z);
  u.w = f2b(-w.w * pi * at.w);
  *(ushort4*)(oc + ((size_t)b*CN + n)*CC + c) = u;
}

// ---------------- launch ----------------
extern "C" void kernel_launch(void* const* d_in, const int* in_sizes, int n_in,
                              void* d_out, int out_size, void* d_ws, size_t ws_size,
                              hipStream_t stream) {
  (void)in_sizes; (void)n_in; (void)out_size; (void)ws_size;
  const float* x     = (const float*)d_in[0];
  const float* qkvw  = (const float*)d_in[1];
  const float* temp  = (const float*)d_in[2];
  const float* projw = (const float*)d_in[3];
  const float* projb = (const float*)d_in[4];
  const float* c1w   = (const float*)d_in[5];
  const float* g1=(const float*)d_in[6], *b1=(const float*)d_in[7], *m1=(const float*)d_in[8], *v1=(const float*)d_in[9];
  const float* c2w   = (const float*)d_in[10];
  const float* g2=(const float*)d_in[11], *b2=(const float*)d_in[12], *m2=(const float*)d_in[13], *v2=(const float*)d_in[14];
  float* out = (float*)d_out;
  char* ws = (char*)d_ws;

  constexpr size_t SZ_XB  = (size_t)CB*CN*CC*2;   // 32 MiB (bf16 b,n,c)
  constexpr size_t SZ_WF  = (size_t)CB*CN*CC*4;   // 64 MiB (fp32 b,n,c)
  u16*   xb   = (u16*)(ws);                        // bf16 [b][n][c]; reused as out_c
  float* Wf   = (float*)(ws + SZ_XB);              // fp32 [b][n][c]; bytes reused as yb
  u16*   yb   = (u16*)(ws + SZ_XB);                // bf16 [b][n][512] (same bytes as Wf)
  u16*   xrb  = (u16*)(ws + SZ_XB + SZ_WF);        // bf16 [b][n][c]
  float* xrf  = out;                               // fp32 [b][c][n] staged in d_out
  char*  wts  = ws + SZ_XB + SZ_WF + SZ_XB;
  u16* qkvb = (u16*)wts;
  u16* pjb  = qkvb + 65536;
  u16* c1b  = pjb + 65536;
  u16* c2b  = c1b + 131072;
  float* s1 = (float*)(wts + 786432);
  float* o1 = s1 + 512;
  float* s2 = o1 + 512;
  float* o2 = s2 + 256;
  float* Pi = (float*)(wts + 786432 + 8192);
  float* nrm2 = Pi + (size_t)CB*CH*CN;
  float* sumPi = nrm2 + CB*CC;
  float* dots  = sumPi + CB*CH;
  float* attnv = dots + CB*CC;

  hipMemsetAsync(nrm2, 0, (size_t)(CB*CC + CB*CH + CB*CC)*4, stream);
  k_prep_w<<<1536, 256, 0, stream>>>(qkvw, projw, c1w, c2w, qkvb, pjb, c1b, c2b);
  k_prep_bn<<<3, 256, 0, stream>>>(g1,b1,m1,v1,g2,b2,m2,v2,s1,o1,s2,o2);
  k_tr<<<dim3(CB, CC/32, CN/32), 256, 0, stream>>>(x, xb);
  // W = x3 @ qkv^T  -> Wf [b][n][c] fp32
  k_gemm<256,256,0><<<dim3(CN/128, 2, CB), 256, 0, stream>>>(qkvb, xb, Wf, nullptr, nullptr, nullptr, nullptr);
  k_nrm2<<<dim3(CB, CN/128), 256, 0, stream>>>(Wf, nrm2);
  k_pi<<<dim3(CB, CN/64), 256, 0, stream>>>(Wf, nrm2, temp, Pi, sumPi);
  k_dots<<<dim3(CB, CN/128), 256, 0, stream>>>(Wf, Pi, dots);
  k_attn<<<CB, 256, 0, stream>>>(dots, sumPi, attnv);
  k_outc<<<(CB*CN*CC/4)/256, 256, 0, stream>>>(Wf, Pi, attnv, xb);
  // a = out_c @ proj^T + proj_b; xr = x + a  -> xrf fp32 [b][c][n] (in d_out), xrb bf16 [b][n][c]
  k_gemm<256,256,1><<<dim3(CN/128, 2, CB), 256, 0, stream>>>(pjb, xb, xrf, xrb, projb, x, nullptr);
  // y = silu(bn1(conv1(xr))) -> yb bf16 [b][n][512]
  k_gemm<512,256,2><<<dim3(CN/128, 4, CB), 256, 0, stream>>>(c1b, xrb, nullptr, yb, s1, o1, nullptr);
  // out = xr + bn2(conv2(y)) -> fp32 [b][c][n]
  k_gemm<256,512,3><<<dim3(CN/128, 2, CB), 256, 0, stream>>>(c2b, yb, out, nullptr, s2, o2, xrf);
}

// Round 4
// 215.457 us; speedup vs baseline: 1.4355x; 1.4355x over previous
//
#include <hip/hip_runtime.h>
#include <hip/hip_bf16.h>
#include <stdint.h>

typedef unsigned short u16;
using bf16x8 = __attribute__((ext_vector_type(8))) short;
using f32x4  = __attribute__((ext_vector_type(4))) float;

#define DEVI static __device__ __forceinline__

constexpr int CB = 16;     // batch
constexpr int CC = 256;    // channels
constexpr int CN = 4096;   // tokens
constexpr int CH = 4;      // heads

DEVI u16 f2b(float f){
  union { float f; uint32_t u; } v; v.f = f;
  return (u16)((v.u + 0x7FFFu + ((v.u >> 16) & 1u)) >> 16);
}
DEVI float b2f(u16 u){
  union { uint32_t u; float f; } v; v.u = ((uint32_t)u) << 16; return v.f;
}

// ---------------- prep: weights -> bf16, BN constants ----------------
__global__ __launch_bounds__(256) void k_prep_w(const float* __restrict__ qkv, const float* __restrict__ pj,
    const float* __restrict__ c1, const float* __restrict__ c2,
    u16* __restrict__ qkvb, u16* __restrict__ pjb, u16* __restrict__ c1b, u16* __restrict__ c2b){
  int id = blockIdx.x * 256 + threadIdx.x;
  if (id < 65536) qkvb[id] = f2b(qkv[id]);
  else if (id < 131072) pjb[id - 65536] = f2b(pj[id - 65536]);
  else if (id < 262144) c1b[id - 131072] = f2b(c1[id - 131072]);
  else c2b[id - 262144] = f2b(c2[id - 262144]);
}

__global__ __launch_bounds__(256) void k_prep_bn(const float* __restrict__ g1,const float* __restrict__ b1,
    const float* __restrict__ m1,const float* __restrict__ v1,
    const float* __restrict__ g2,const float* __restrict__ b2,
    const float* __restrict__ m2,const float* __restrict__ v2,
    float* __restrict__ s1,float* __restrict__ o1,float* __restrict__ s2,float* __restrict__ o2){
  int id = blockIdx.x*256 + threadIdx.x;
  if (id < 512){ float s = g1[id] * rsqrtf(v1[id] + 1e-5f); s1[id] = s; o1[id] = b1[id] - m1[id]*s; }
  else if (id < 768){ int c = id - 512; float s = g2[c] * rsqrtf(v2[c] + 1e-5f); s2[c] = s; o2[c] = b2[c] - m2[c]*s; }
}

// ---------------- transpose x [b][c][n] -> bf16 [b][n][c] ----------------
__global__ __launch_bounds__(256) void k_tr(const float* __restrict__ x, u16* __restrict__ xb){
  __shared__ float t[32][33];
  int b = blockIdx.x, c0 = blockIdx.y*32, n0 = blockIdx.z*32;
  int tr = threadIdx.x >> 5, tc = threadIdx.x & 31;
  const float* xp = x + ((size_t)b*CC + c0)*CN + n0;
  #pragma unroll
  for (int p=0;p<4;p++) t[tr + p*8][tc] = xp[(size_t)(tr + p*8)*CN + tc];
  __syncthreads();
  u16* op = xb + ((size_t)b*CN + n0)*CC + c0;
  #pragma unroll
  for (int p=0;p<4;p++) op[(size_t)(tr + p*8)*CC + tc] = f2b(t[tc][tr + p*8]);
}

// ---------------- GEMM: C[m][n] = sum_k A[m][k] * Act[b][n][k] ----------------
// Double-buffered LDS (minimum 2-phase T3 recipe): stage(t+1) issued before
// compute(t); __syncthreads() (vmcnt0+lgkmcnt0+barrier) once per tile.
// EPI 0: ob[b][n][M_] = bf16(v); atomicAdd of[b*CC+c] += sum_n v^2   (nrm2)
// EPI 1: r = v + e0[c] + e1[b][c][n] (fp32 x); ob[b][n][M_] = bf16(r)
// EPI 2: r = silu(v*e0[c]+e1[c]); ob[b][n][M_] = bf16(r)
// EPI 3: of[b][c][n] = v*e0[c]+e1[c] + b2f(eb[b][n][c])
template<int M_, int K_, int EPI>
__global__ __launch_bounds__(256) void k_gemm(
    const u16* __restrict__ Aw, const u16* __restrict__ Act,
    float* of, u16* __restrict__ ob,
    const float* __restrict__ e0, const float* __restrict__ e1,
    const u16* __restrict__ eb)
{
  __shared__ __align__(16) u16 As[2][128*64];
  __shared__ __align__(16) u16 Bs[2][128*64];
  const int t = threadIdx.x;
  const int lane = t & 63, wave = t >> 6;
  const int wr = wave >> 1, wc = wave & 1;
  const int lg = lane >> 4, lr = lane & 15;
  // linearize + XCD-aware swizzle (nwg % 8 == 0 for all our grids)
  const int gx = gridDim.x, gy = gridDim.y;
  const int nwg = gx * gy * gridDim.z;
  const int id0 = blockIdx.x + gx*(blockIdx.y + gy*blockIdx.z);
  const int id  = (id0 & 7)*(nwg >> 3) + (id0 >> 3);
  const int bx = id % gx; const int rem = id / gx;
  const int by = rem % gy; const int bz = rem / gy;
  const int n0 = bx * 128, m0 = by * 128, b = bz;
  const u16* Ag = Aw + (size_t)m0 * K_;
  const u16* Bg = Act + ((size_t)b * CN + n0) * K_;
  f32x4 acc[4][4] = {};
  constexpr int NT = K_/64;
  auto stage = [&](int p, int kt){
    #pragma unroll
    for (int i=0;i<4;i++){
      int off = (i*256 + t) * 8;
      int m = off >> 6, gq = (off >> 3) & 7;
      int kk = (gq ^ (m & 7)) * 8;            // inverse-swizzled global k
      __builtin_amdgcn_global_load_lds(
        (__attribute__((address_space(1))) void*)(Ag + (size_t)m*K_ + kt*64 + kk),
        (__attribute__((address_space(3))) void*)(&As[p][(i*256 + wave*64)*8]), 16, 0, 0);
      __builtin_amdgcn_global_load_lds(
        (__attribute__((address_space(1))) void*)(Bg + (size_t)m*K_ + kt*64 + kk),
        (__attribute__((address_space(3))) void*)(&Bs[p][(i*256 + wave*64)*8]), 16, 0, 0);
    }
  };
  stage(0, 0);
  __syncthreads();
  for (int kt = 0; kt < NT; ++kt){
    const int cur = kt & 1;
    if (kt + 1 < NT) stage(cur ^ 1, kt + 1);   // loads fly during compute
    #pragma unroll
    for (int s=0;s<2;s++){
      bf16x8 af[4], bfv[4];
      #pragma unroll
      for (int mi=0;mi<4;mi++){
        int r = wr*64 + mi*16 + lr;
        af[mi] = *(const bf16x8*)(&As[cur][r*64 + (((s*4+lg) ^ (r & 7)) * 8)]);
      }
      #pragma unroll
      for (int ni=0;ni<4;ni++){
        int r = wc*64 + ni*16 + lr;
        bfv[ni] = *(const bf16x8*)(&Bs[cur][r*64 + (((s*4+lg) ^ (r & 7)) * 8)]);
      }
      #pragma unroll
      for (int mi=0;mi<4;mi++)
        #pragma unroll
        for (int ni=0;ni<4;ni++)
          acc[mi][ni] = __builtin_amdgcn_mfma_f32_16x16x32_bf16(af[mi], bfv[ni], acc[mi][ni], 0, 0, 0);
    }
    __syncthreads();   // drains vmcnt (tile kt+1 staged) + protects buffer reuse
  }
  #pragma unroll
  for (int mi=0;mi<4;mi++){
    const int mb = m0 + wr*64 + mi*16 + lg*4;
    float sq[4] = {0.f,0.f,0.f,0.f};
    #pragma unroll
    for (int ni=0;ni<4;ni++){
      const int n = n0 + wc*64 + ni*16 + lr;
      f32x4 v = acc[mi][ni];
      if constexpr (EPI == 0){
        ushort4 u;
        #pragma unroll
        for (int j=0;j<4;j++){ ((u16*)&u)[j] = f2b(v[j]); sq[j] += v[j]*v[j]; }
        *(ushort4*)(ob + ((size_t)b*CN + n)*M_ + mb) = u;
      } else if constexpr (EPI == 1){
        ushort4 u;
        #pragma unroll
        for (int j=0;j<4;j++){
          size_t ix = ((size_t)b*CC + mb + j)*CN + n;
          ((u16*)&u)[j] = f2b(v[j] + e0[mb + j] + e1[ix]);
        }
        *(ushort4*)(ob + ((size_t)b*CN + n)*M_ + mb) = u;
      } else if constexpr (EPI == 2){
        ushort4 u;
        #pragma unroll
        for (int j=0;j<4;j++){
          float r = v[j]*e0[mb+j] + e1[mb+j];
          r = r / (1.f + __expf(-r));
          ((u16*)&u)[j] = f2b(r);
        }
        *(ushort4*)(ob + ((size_t)b*CN + n)*M_ + mb) = u;
      } else {
        ushort4 xw = *(const ushort4*)(eb + ((size_t)b*CN + n)*M_ + mb);
        #pragma unroll
        for (int j=0;j<4;j++){
          size_t ix = ((size_t)b*CC + mb + j)*CN + n;
          of[ix] = v[j]*e0[mb+j] + e1[mb+j] + b2f(((const u16*)&xw)[j]);
        }
      }
    }
    if constexpr (EPI == 0){
      #pragma unroll
      for (int off=1; off<16; off<<=1)
        #pragma unroll
        for (int j=0;j<4;j++) sq[j] += __shfl_xor(sq[j], off);
      if (lr == 0){
        #pragma unroll
        for (int j=0;j<4;j++) atomicAdd(&of[b*CC + mb + j], sq[j]);
      }
    }
  }
}

// ---------------- fused stats: s, head-softmax Pi, sumPi, dotsU ----------------
// dots = dotsU / (sumPi+1e-8) computed later in k_outc.
__global__ __launch_bounds__(256) void k_stats(const u16* __restrict__ W, const float* __restrict__ nrm2,
    const float* __restrict__ temp, float* __restrict__ Pi, float* __restrict__ sumPi,
    float* __restrict__ dotsU){
  __shared__ float red[4][256];
  const int b = blockIdx.x, n0 = blockIdx.y * 64;
  const int t = threadIdx.x, lane = t & 63, wave = t >> 6;
  const int grp = lane >> 4, gl = lane & 15;
  const float th = temp[grp];
  const float4 nr = *(const float4*)(nrm2 + b*CC + 4*lane);
  const float i0 = 1.f/fmaxf(nr.x,1e-24f), i1 = 1.f/fmaxf(nr.y,1e-24f);
  const float i2 = 1.f/fmaxf(nr.z,1e-24f), i3 = 1.f/fmaxf(nr.w,1e-24f);
  float accp = 0.f, d0=0.f, d1=0.f, d2=0.f, d3=0.f;
  for (int i=0;i<16;i++){
    int n = n0 + wave*16 + i;
    ushort4 wu = *(const ushort4*)(W + ((size_t)b*CN + n)*CC + 4*lane);
    float w0=b2f(wu.x), w1=b2f(wu.y), w2=b2f(wu.z), w3=b2f(wu.w);
    float q0=w0*w0, q1=w1*w1, q2=w2*w2, q3=w3*w3;
    float s = q0*i0 + q1*i1 + q2*i2 + q3*i3;
    #pragma unroll
    for (int off=1; off<16; off<<=1) s += __shfl_xor(s, off);
    s *= th;
    float sA=__shfl(s,0), sB=__shfl(s,16), sC=__shfl(s,32), sD=__shfl(s,48);
    float mx = fmaxf(fmaxf(sA,sB), fmaxf(sC,sD));
    float eA=__expf(sA-mx), eB=__expf(sB-mx), eC=__expf(sC-mx), eD=__expf(sD-mx);
    float den = eA+eB+eC+eD;
    float pih = ((grp==0)?eA:(grp==1)?eB:(grp==2)?eC:eD)/den;
    if (gl == 0){ Pi[((size_t)b*CH + grp)*CN + n] = pih; accp += pih; }
    d0 += pih*q0; d1 += pih*q1; d2 += pih*q2; d3 += pih*q3;
  }
  if (gl == 0) atomicAdd(&sumPi[b*CH + grp], accp);
  red[wave][4*lane+0]=d0; red[wave][4*lane+1]=d1; red[wave][4*lane+2]=d2; red[wave][4*lane+3]=d3;
  __syncthreads();
  float sm = red[0][t]+red[1][t]+red[2][t]+red[3][t];
  atomicAdd(&dotsU[b*CC + t], sm);
}

// ---------------- out_c = -(w * Pi) * attn, attn computed inline ----------------
__global__ __launch_bounds__(256) void k_outc(const u16* __restrict__ W, const float* __restrict__ Pi,
    const float* __restrict__ dotsU, const float* __restrict__ sumPi, u16* __restrict__ oc){
  size_t id = (size_t)blockIdx.x * 256 + threadIdx.x;
  int c = ((int)(id & 63)) * 4;
  int n = (int)((id >> 6) & (CN - 1));
  int b = (int)(id >> 18);
  int h = c >> 6;
  ushort4 wu = *(const ushort4*)(W + ((size_t)b*CN + n)*CC + c);
  float pi = Pi[((size_t)b*CH + h)*CN + n];
  float sp = sumPi[b*CH + h] + 1e-8f;
  float4 du = *(const float4*)(dotsU + b*CC + c);
  float a0 = sp/(sp + du.x), a1 = sp/(sp + du.y), a2 = sp/(sp + du.z), a3 = sp/(sp + du.w);
  ushort4 u;
  u.x = f2b(-b2f(wu.x) * pi * a0);
  u.y = f2b(-b2f(wu.y) * pi * a1);
  u.z = f2b(-b2f(wu.z) * pi * a2);
  u.w = f2b(-b2f(wu.w) * pi * a3);
  *(ushort4*)(oc + ((size_t)b*CN + n)*CC + c) = u;
}

// ---------------- launch ----------------
extern "C" void kernel_launch(void* const* d_in, const int* in_sizes, int n_in,
                              void* d_out, int out_size, void* d_ws, size_t ws_size,
                              hipStream_t stream) {
  (void)in_sizes; (void)n_in; (void)out_size; (void)ws_size;
  const float* x     = (const float*)d_in[0];
  const float* qkvw  = (const float*)d_in[1];
  const float* temp  = (const float*)d_in[2];
  const float* projw = (const float*)d_in[3];
  const float* projb = (const float*)d_in[4];
  const float* c1w   = (const float*)d_in[5];
  const float* g1=(const float*)d_in[6], *b1=(const float*)d_in[7], *m1=(const float*)d_in[8], *v1=(const float*)d_in[9];
  const float* c2w   = (const float*)d_in[10];
  const float* g2=(const float*)d_in[11], *b2=(const float*)d_in[12], *m2=(const float*)d_in[13], *v2=(const float*)d_in[14];
  float* out = (float*)d_out;
  char* ws = (char*)d_ws;

  constexpr size_t MB = 1024*1024;
  // region A [0,64MB): xb/oc bf16 [b][n][c] (32MB) until GEMM2; then yb bf16 [b][n][512] (64MB)
  u16* xb  = (u16*)(ws);
  u16* oc  = xb;
  u16* yb  = (u16*)(ws);
  u16* xrb = (u16*)(ws + 64*MB);     // bf16 [b][n][c] (32MB)
  u16* Wb  = (u16*)(ws + 96*MB);     // bf16 [b][n][c] (32MB)
  char* wts = ws + 128*MB;
  u16* qkvb = (u16*)wts;
  u16* pjb  = qkvb + 65536;
  u16* c1b  = pjb + 65536;
  u16* c2b  = c1b + 131072;
  float* s1 = (float*)(wts + 786432);
  float* o1 = s1 + 512;
  float* s2 = o1 + 512;
  float* o2 = s2 + 256;
  float* Pi = (float*)(wts + 786432 + 8192);
  float* nrm2  = Pi + (size_t)CB*CH*CN;
  float* sumPi = nrm2 + CB*CC;
  float* dotsU = sumPi + CB*CH;

  hipMemsetAsync(nrm2, 0, (size_t)(CB*CC + CB*CH + CB*CC)*4, stream);
  k_prep_w<<<1536, 256, 0, stream>>>(qkvw, projw, c1w, c2w, qkvb, pjb, c1b, c2b);
  k_prep_bn<<<3, 256, 0, stream>>>(g1,b1,m1,v1,g2,b2,m2,v2,s1,o1,s2,o2);
  k_tr<<<dim3(CB, CC/32, CN/32), 256, 0, stream>>>(x, xb);
  // W = x3 @ qkv^T -> Wb bf16 [b][n][c] + nrm2 atomics
  k_gemm<256,256,0><<<dim3(CN/128, 2, CB), 256, 0, stream>>>(qkvb, xb, nrm2, Wb, nullptr, nullptr, nullptr);
  // head-softmax Pi, sumPi, unnormalized dots
  k_stats<<<dim3(CB, CN/64), 256, 0, stream>>>(Wb, nrm2, temp, Pi, sumPi, dotsU);
  // out_c (attn inline)
  k_outc<<<(CB*CN*CC/4)/256, 256, 0, stream>>>(Wb, Pi, dotsU, sumPi, oc);
  // xr = x + proj(out_c) + bias -> xrb bf16 [b][n][c]
  k_gemm<256,256,1><<<dim3(CN/128, 2, CB), 256, 0, stream>>>(pjb, oc, nullptr, xrb, projb, x, nullptr);
  // y = silu(bn1(conv1(xr))) -> yb bf16 [b][n][512]
  k_gemm<512,256,2><<<dim3(CN/128, 4, CB), 256, 0, stream>>>(c1b, xrb, nullptr, yb, s1, o1, nullptr);
  // out = xr + bn2(conv2(y)) -> fp32 [b][c][n]
  k_gemm<256,512,3><<<dim3(CN/128, 2, CB), 256, 0, stream>>>(c2b, yb, out, nullptr, s2, o2, xrb);
}